// Round 1
// baseline (4161.554 us; speedup 1.0000x reference)
//
#include <hip/hip_runtime.h>
#include <cstdint>
#include <cstddef>

// Problem constants (match reference)
#define Bq 64
#define Tq 512
#define Sq 4
#define Hq 512
#define Vq 10000

// ---------------------------------------------------------------------------
// K1: Z[r] = logsumexp_v U[r, :]  for r in [0, S*H)   (rows of length V)
// ---------------------------------------------------------------------------
__global__ __launch_bounds__(256) void k_row_lse(const float* __restrict__ U,
                                                 float* __restrict__ Z) {
  const int r = blockIdx.x;
  const int tid = threadIdx.x;
  const int lane = tid & 63, wid = tid >> 6;
  __shared__ float sred[8];
  const float4* row = (const float4*)(U + (size_t)r * Vq);  // V=10000 -> 2500 float4
  float m = -1e30f;
  for (int i = tid; i < Vq / 4; i += 256) {
    float4 x = row[i];
    m = fmaxf(fmaxf(m, fmaxf(x.x, x.y)), fmaxf(x.z, x.w));
  }
#pragma unroll
  for (int o = 32; o; o >>= 1) m = fmaxf(m, __shfl_xor(m, o));
  if (lane == 0) sred[wid] = m;
  __syncthreads();
  const float M = fmaxf(fmaxf(sred[0], sred[1]), fmaxf(sred[2], sred[3]));
  float s = 0.f;
  for (int i = tid; i < Vq / 4; i += 256) {
    float4 x = row[i];
    s += expf(x.x - M) + expf(x.y - M) + expf(x.z - M) + expf(x.w - M);
  }
#pragma unroll
  for (int o = 32; o; o >>= 1) s += __shfl_xor(s, o);
  if (lane == 0) sred[4 + wid] = s;
  __syncthreads();
  if (tid == 0) {
    Z[r] = M + logf(sred[4] + sred[5] + sred[6] + sred[7]);
  }
}

// ---------------------------------------------------------------------------
// K2: C[h] = 0.25 * sum_s Z[s*H + h]
// ---------------------------------------------------------------------------
__global__ __launch_bounds__(512) void k_cvec(const float* __restrict__ Z,
                                              float* __restrict__ C) {
  const int h = threadIdx.x;
  C[h] = 0.25f * (Z[h] + Z[Hq + h] + Z[2 * Hq + h] + Z[3 * Hq + h]);
}

// ---------------------------------------------------------------------------
// K3: E[j,k] = softmax over k of tran[j,:]   (exp of log_softmax rows)
// ---------------------------------------------------------------------------
__global__ __launch_bounds__(512) void k_tran_softmax(const float* __restrict__ tr,
                                                      float* __restrict__ E) {
  const int j = blockIdx.x, tid = threadIdx.x;
  const int lane = tid & 63, wid = tid >> 6;
  __shared__ float sred[16];
  const float t = tr[j * Hq + tid];
  float m = t;
#pragma unroll
  for (int o = 32; o; o >>= 1) m = fmaxf(m, __shfl_xor(m, o));
  if (lane == 0) sred[wid] = m;
  __syncthreads();
  float M = sred[0];
#pragma unroll
  for (int q = 1; q < 8; ++q) M = fmaxf(M, sred[q]);
  const float e = expf(t - M);
  float s = e;
#pragma unroll
  for (int o = 32; o; o >>= 1) s += __shfl_xor(s, o);
  if (lane == 0) sred[8 + wid] = s;
  __syncthreads();
  float S = 0.f;
#pragma unroll
  for (int q = 0; q < 8; ++q) S += sred[8 + q];
  E[j * Hq + tid] = e / S;
}

// ---------------------------------------------------------------------------
// K4: transpose U (S,H,V) -> UT (S,V,H) so per-(s,v) h-vectors are contiguous
// ---------------------------------------------------------------------------
__global__ __launch_bounds__(256) void k_transpose(const float* __restrict__ U,
                                                   float* __restrict__ UT) {
  __shared__ float tile[32][33];
  const int s = blockIdx.z;
  const int v0 = blockIdx.x * 32, h0 = blockIdx.y * 32;
  const int tx = threadIdx.x, ty = threadIdx.y;  // 32 x 8
#pragma unroll
  for (int q = 0; q < 4; ++q) {
    const int h = h0 + ty + q * 8;
    const int v = v0 + tx;
    if (v < Vq) tile[ty + q * 8][tx] = U[((size_t)s * Hq + h) * Vq + v];
  }
  __syncthreads();
#pragma unroll
  for (int q = 0; q < 4; ++q) {
    const int v = v0 + ty + q * 8;
    if (v < Vq) UT[((size_t)s * Vq + v) * Hq + h0 + tx] = tile[tx][ty + q * 8];
  }
}

// ---------------------------------------------------------------------------
// Emission for one (b,t), state k:  0.25*sum_s table[s][obs_s][k] - C[k]
// ---------------------------------------------------------------------------
__device__ __forceinline__ float emis_at(const float* __restrict__ U,
                                         const float* __restrict__ UT,
                                         const float* __restrict__ C,
                                         const int* __restrict__ ob, int k,
                                         int use_ut) {
  float e;
  if (use_ut) {
    e = UT[((size_t)0 * Vq + ob[0]) * Hq + k] +
        UT[((size_t)1 * Vq + ob[1]) * Hq + k] +
        UT[((size_t)2 * Vq + ob[2]) * Hq + k] +
        UT[((size_t)3 * Vq + ob[3]) * Hq + k];
  } else {
    e = U[((size_t)0 * Hq + k) * Vq + ob[0]] +
        U[((size_t)1 * Hq + k) * Vq + ob[1]] +
        U[((size_t)2 * Hq + k) * Vq + ob[2]] +
        U[((size_t)3 * Hq + k) * Vq + ob[3]];
  }
  return 0.25f * e - C[k];
}

// ---------------------------------------------------------------------------
// K5: forward recursion. One workgroup per batch element b; 512 threads.
// Thread k owns alpha_k in a register. Per step:
//   M = max_k alpha; w_k = exp(alpha_k - M)            (LDS broadcast)
//   part = w . E   (j split 4 ways, k-quads via float4 loads of E rows)
//   alpha_k = em[t,k] + M + log(sum_j w_j E[j,k])
// Early-exits at t = lengths[b]-1, then out[b] = logsumexp_k alpha.
// ---------------------------------------------------------------------------
__global__ __launch_bounds__(512) void k_forward(const int* __restrict__ obs,
                                                 const int* __restrict__ lengths,
                                                 const float* __restrict__ U,
                                                 const float* __restrict__ UT,
                                                 const float* __restrict__ C,
                                                 const float* __restrict__ E,
                                                 const float* __restrict__ pri,
                                                 float* __restrict__ out,
                                                 int use_ut) {
  const int b = blockIdx.x;
  const int tid = threadIdx.x;           // = state k
  const int lane = tid & 63, wid = tid >> 6;
  const int L = lengths[b];

  __shared__ float w[Hq];                // 2 KB
  __shared__ float part[4][Hq];          // 8 KB
  __shared__ float red[16];

  // t = 0
  const int* ob0 = obs + ((size_t)b * Tq + 0) * Sq;
  float a = emis_at(U, UT, C, ob0, tid, use_ut) + pri[tid];

  const int jg = tid >> 7;   // j-group 0..3 (each covers 128 j)
  const int i = tid & 127;   // k-quad index: k = 4*i .. 4*i+3
  const float4* E4 = (const float4*)E;   // row j = E4[j*128 + i]

  for (int t = 1; t < L; ++t) {
    // issue emission gathers early (independent of the reduce/matvec)
    const int* obt = obs + ((size_t)b * Tq + t) * Sq;
    const float emt = emis_at(U, UT, C, obt, tid, use_ut);

    // block max of alpha
    float m = a;
#pragma unroll
    for (int o = 32; o; o >>= 1) m = fmaxf(m, __shfl_xor(m, o));
    if (lane == 0) red[wid] = m;
    __syncthreads();
    float M = red[0];
#pragma unroll
    for (int q = 1; q < 8; ++q) M = fmaxf(M, red[q]);

    w[tid] = expf(a - M);
    __syncthreads();

    // matvec: this thread accumulates k = 4i..4i+3 over j in [jg*128, jg*128+128)
    float4 acc = {0.f, 0.f, 0.f, 0.f};
    const int j0 = jg * 128;
#pragma unroll 4
    for (int jj = 0; jj < 128; ++jj) {
      const int j = j0 + jj;
      const float wj = w[j];
      const float4 e = E4[(size_t)j * 128 + i];
      acc.x += wj * e.x;
      acc.y += wj * e.y;
      acc.z += wj * e.z;
      acc.w += wj * e.w;
    }
    ((float4*)part[jg])[i] = acc;
    __syncthreads();

    const float ssum = part[0][tid] + part[1][tid] + part[2][tid] + part[3][tid];
    a = emt + M + logf(ssum);
    __syncthreads();
  }

  // out[b] = logsumexp_k a
  float m = a;
#pragma unroll
  for (int o = 32; o; o >>= 1) m = fmaxf(m, __shfl_xor(m, o));
  if (lane == 0) red[wid] = m;
  __syncthreads();
  float M = red[0];
#pragma unroll
  for (int q = 1; q < 8; ++q) M = fmaxf(M, red[q]);
  float e = expf(a - M);
#pragma unroll
  for (int o = 32; o; o >>= 1) e += __shfl_xor(e, o);
  if (lane == 0) red[8 + wid] = e;
  __syncthreads();
  if (tid == 0) {
    float S = 0.f;
#pragma unroll
    for (int q = 0; q < 8; ++q) S += red[8 + q];
    out[b] = M + logf(S);
  }
}

// ---------------------------------------------------------------------------
// Workspace layout (floats):
//   E  : [0, 262144)               softmax(tran)        1 MB
//   Z  : [262144, 264192)          per-(s,h) row LSE    8 KB
//   C  : [264192, 264704)          emission constant    2 KB
//   UT : [264704, 264704+20480000) transposed table     81.9 MB
// ---------------------------------------------------------------------------
extern "C" void kernel_launch(void* const* d_in, const int* in_sizes, int n_in,
                              void* d_out, int out_size, void* d_ws,
                              size_t ws_size, hipStream_t stream) {
  const int* obs = (const int*)d_in[0];
  const int* lengths = (const int*)d_in[1];
  const float* U = (const float*)d_in[2];       // unnormalized_emis (S,H,V)
  const float* tran = (const float*)d_in[3];    // unnormalized_tran (H,H)
  const float* pri = (const float*)d_in[4];     // log_state_priors (H,)
  float* out = (float*)d_out;

  float* ws = (float*)d_ws;
  float* E = ws;
  float* Z = ws + 262144;
  float* C = ws + 264192;
  float* UT = ws + 264704;

  const size_t need_ut_bytes = (264704ull + 20480000ull) * 4ull;
  const int use_ut = (ws_size >= need_ut_bytes) ? 1 : 0;

  k_row_lse<<<Sq * Hq, 256, 0, stream>>>(U, Z);
  k_cvec<<<1, 512, 0, stream>>>(Z, C);
  k_tran_softmax<<<Hq, 512, 0, stream>>>(tran, E);
  if (use_ut) {
    dim3 grid((Vq + 31) / 32, Hq / 32, Sq);
    k_transpose<<<grid, dim3(32, 8), 0, stream>>>(U, UT);
  }
  k_forward<<<Bq, 512, 0, stream>>>(obs, lengths, U, UT, C, E, pri, out, use_ut);
}

// Round 2
// 2496.179 us; speedup vs baseline: 1.6672x; 1.6672x over previous
//
#include <hip/hip_runtime.h>
#include <hip/hip_fp16.h>
#include <cstdint>
#include <cstddef>

// Problem constants (match reference)
#define Bq 64
#define Tq 512
#define Sq 4
#define Hq 512
#define Vq 10000

// ---------------------------------------------------------------------------
// K1: Z[r] = logsumexp_v U[r, :]  for r in [0, S*H)   (rows of length V)
// ---------------------------------------------------------------------------
__global__ __launch_bounds__(256) void k_row_lse(const float* __restrict__ U,
                                                 float* __restrict__ Z) {
  const int r = blockIdx.x;
  const int tid = threadIdx.x;
  const int lane = tid & 63, wid = tid >> 6;
  __shared__ float sred[8];
  const float4* row = (const float4*)(U + (size_t)r * Vq);  // V=10000 -> 2500 float4
  float m = -1e30f;
  for (int i = tid; i < Vq / 4; i += 256) {
    float4 x = row[i];
    m = fmaxf(fmaxf(m, fmaxf(x.x, x.y)), fmaxf(x.z, x.w));
  }
#pragma unroll
  for (int o = 32; o; o >>= 1) m = fmaxf(m, __shfl_xor(m, o));
  if (lane == 0) sred[wid] = m;
  __syncthreads();
  const float M = fmaxf(fmaxf(sred[0], sred[1]), fmaxf(sred[2], sred[3]));
  float s = 0.f;
  for (int i = tid; i < Vq / 4; i += 256) {
    float4 x = row[i];
    s += expf(x.x - M) + expf(x.y - M) + expf(x.z - M) + expf(x.w - M);
  }
#pragma unroll
  for (int o = 32; o; o >>= 1) s += __shfl_xor(s, o);
  if (lane == 0) sred[4 + wid] = s;
  __syncthreads();
  if (tid == 0) {
    Z[r] = M + logf(sred[4] + sred[5] + sred[6] + sred[7]);
  }
}

// ---------------------------------------------------------------------------
// K2: C[h] = 0.25 * sum_s Z[s*H + h]
// ---------------------------------------------------------------------------
__global__ __launch_bounds__(512) void k_cvec(const float* __restrict__ Z,
                                              float* __restrict__ C) {
  const int h = threadIdx.x;
  C[h] = 0.25f * (Z[h] + Z[Hq + h] + Z[2 * Hq + h] + Z[3 * Hq + h]);
}

// ---------------------------------------------------------------------------
// K3: E16[j,k] = (half) softmax_k(tran[j,:])
// ---------------------------------------------------------------------------
__global__ __launch_bounds__(512) void k_tran_softmax(const float* __restrict__ tr,
                                                      __half* __restrict__ E16) {
  const int j = blockIdx.x, tid = threadIdx.x;
  const int lane = tid & 63, wid = tid >> 6;
  __shared__ float sred[16];
  const float t = tr[j * Hq + tid];
  float m = t;
#pragma unroll
  for (int o = 32; o; o >>= 1) m = fmaxf(m, __shfl_xor(m, o));
  if (lane == 0) sred[wid] = m;
  __syncthreads();
  float M = sred[0];
#pragma unroll
  for (int q = 1; q < 8; ++q) M = fmaxf(M, sred[q]);
  const float e = expf(t - M);
  float s = e;
#pragma unroll
  for (int o = 32; o; o >>= 1) s += __shfl_xor(s, o);
  if (lane == 0) sred[8 + wid] = s;
  __syncthreads();
  float S = 0.f;
#pragma unroll
  for (int q = 0; q < 8; ++q) S += sred[8 + q];
  E16[j * Hq + tid] = __float2half(e / S);
}

// ---------------------------------------------------------------------------
// K4: transpose U (S,H,V) -> UT (S,V,H) so per-(s,v) h-vectors are contiguous
// ---------------------------------------------------------------------------
__global__ __launch_bounds__(256) void k_transpose(const float* __restrict__ U,
                                                   float* __restrict__ UT) {
  __shared__ float tile[32][33];
  const int s = blockIdx.z;
  const int v0 = blockIdx.x * 32, h0 = blockIdx.y * 32;
  const int tx = threadIdx.x, ty = threadIdx.y;  // 32 x 8
#pragma unroll
  for (int q = 0; q < 4; ++q) {
    const int h = h0 + ty + q * 8;
    const int v = v0 + tx;
    if (v < Vq) tile[ty + q * 8][tx] = U[((size_t)s * Hq + h) * Vq + v];
  }
  __syncthreads();
#pragma unroll
  for (int q = 0; q < 4; ++q) {
    const int v = v0 + ty + q * 8;
    if (v < Vq) UT[((size_t)s * Vq + v) * Hq + h0 + tx] = tile[tx][ty + q * 8];
  }
}

// ---------------------------------------------------------------------------
// Emission for one (b,t), state k:  0.25*sum_s table[s][obs_s][k] - C[k]
// ---------------------------------------------------------------------------
__device__ __forceinline__ float emis_at(const float* __restrict__ U,
                                         const float* __restrict__ UT,
                                         const float* __restrict__ C,
                                         const int* __restrict__ ob, int k,
                                         int use_ut) {
  float e;
  if (use_ut) {
    e = UT[((size_t)0 * Vq + ob[0]) * Hq + k] +
        UT[((size_t)1 * Vq + ob[1]) * Hq + k] +
        UT[((size_t)2 * Vq + ob[2]) * Hq + k] +
        UT[((size_t)3 * Vq + ob[3]) * Hq + k];
  } else {
    e = U[((size_t)0 * Hq + k) * Vq + ob[0]] +
        U[((size_t)1 * Hq + k) * Vq + ob[1]] +
        U[((size_t)2 * Hq + k) * Vq + ob[2]] +
        U[((size_t)3 * Hq + k) * Vq + ob[3]];
  }
  return 0.25f * e - C[k];
}

// ---------------------------------------------------------------------------
// K5: forward recursion. One workgroup per batch element b; 512 threads.
// Thread tid owns alpha_{k=tid} in a register. E is f16 (halves per-CU L2
// traffic, which Round-1 counters showed is the roofline: 1MB/56B/cyc=7.8us
// matched the measured 7.85us/step exactly). Per step (3 barriers):
//   B1: publish per-wave max of alpha
//   B2: publish w_j = exp(alpha_j - M)
//   matvec: j-group g=tid>>6 covers 64 j's; k-octet i=tid&63 covers k=8i..8i+7
//   B3: publish partials; alpha_k = em + M + log(sum_g part[g][k])
// Early-exits at t = lengths[b]-1, then out[b] = logsumexp_k alpha.
// ---------------------------------------------------------------------------
__global__ __launch_bounds__(512) void k_forward(const int* __restrict__ obs,
                                                 const int* __restrict__ lengths,
                                                 const float* __restrict__ U,
                                                 const float* __restrict__ UT,
                                                 const float* __restrict__ C,
                                                 const __half* __restrict__ E16,
                                                 const float* __restrict__ pri,
                                                 float* __restrict__ out,
                                                 int use_ut) {
  const int b = blockIdx.x;
  const int tid = threadIdx.x;           // = state k it owns for alpha
  const int lane = tid & 63, wid = tid >> 6;
  const int L = lengths[b];

  __shared__ float w[Hq];                // 2 KB
  __shared__ float part[8][Hq];          // 16 KB
  __shared__ float red[16];

  // t = 0
  const int* ob0 = obs + ((size_t)b * Tq + 0) * Sq;
  float a = emis_at(U, UT, C, ob0, tid, use_ut) + pri[tid];

  const int g = tid >> 6;   // j-group 0..7 (each covers 64 j)
  const int i = tid & 63;   // k-octet index: k = 8*i .. 8*i+7
  const uint4* E16v = (const uint4*)E16;  // row j: E16v[j*64 + i] = 8 halves

  for (int t = 1; t < L; ++t) {
    // issue emission gathers early (independent of the reduce/matvec)
    const int* obt = obs + ((size_t)b * Tq + t) * Sq;
    const float emt = emis_at(U, UT, C, obt, tid, use_ut);

    // block max of alpha
    float m = a;
#pragma unroll
    for (int o = 32; o; o >>= 1) m = fmaxf(m, __shfl_xor(m, o));
    if (lane == 0) red[wid] = m;
    __syncthreads();  // B1: red published; prev-iter part reads complete
    float M = red[0];
#pragma unroll
    for (int q = 1; q < 8; ++q) M = fmaxf(M, red[q]);

    w[tid] = expf(a - M);
    __syncthreads();  // B2: w published

    // matvec: k = 8i..8i+7 over j in [g*64, g*64+64)
    float acc0 = 0.f, acc1 = 0.f, acc2 = 0.f, acc3 = 0.f;
    float acc4 = 0.f, acc5 = 0.f, acc6 = 0.f, acc7 = 0.f;
    const int j0 = g << 6;
#pragma unroll 4
    for (int jj = 0; jj < 64; ++jj) {
      const int j = j0 + jj;
      const float wj = w[j];
      const uint4 e = E16v[(size_t)j * 64 + i];
      const float2 p0 = __half22float2(*reinterpret_cast<const __half2*>(&e.x));
      const float2 p1 = __half22float2(*reinterpret_cast<const __half2*>(&e.y));
      const float2 p2 = __half22float2(*reinterpret_cast<const __half2*>(&e.z));
      const float2 p3 = __half22float2(*reinterpret_cast<const __half2*>(&e.w));
      acc0 += wj * p0.x;
      acc1 += wj * p0.y;
      acc2 += wj * p1.x;
      acc3 += wj * p1.y;
      acc4 += wj * p2.x;
      acc5 += wj * p2.y;
      acc6 += wj * p3.x;
      acc7 += wj * p3.y;
    }
    {
      float4 lo = {acc0, acc1, acc2, acc3};
      float4 hi = {acc4, acc5, acc6, acc7};
      ((float4*)part[g])[2 * i] = lo;
      ((float4*)part[g])[2 * i + 1] = hi;
    }
    __syncthreads();  // B3: part published; w reads complete

    const float ssum = part[0][tid] + part[1][tid] + part[2][tid] +
                       part[3][tid] + part[4][tid] + part[5][tid] +
                       part[6][tid] + part[7][tid];
    a = emt + M + logf(ssum);
    // part reads above happen-before next B1 -> next part write (post-B2) safe
  }

  // out[b] = logsumexp_k a
  float m = a;
#pragma unroll
  for (int o = 32; o; o >>= 1) m = fmaxf(m, __shfl_xor(m, o));
  if (lane == 0) red[wid] = m;
  __syncthreads();
  float M = red[0];
#pragma unroll
  for (int q = 1; q < 8; ++q) M = fmaxf(M, red[q]);
  float e = expf(a - M);
#pragma unroll
  for (int o = 32; o; o >>= 1) e += __shfl_xor(e, o);
  if (lane == 0) red[8 + wid] = e;
  __syncthreads();
  if (tid == 0) {
    float S = 0.f;
#pragma unroll
    for (int q = 0; q < 8; ++q) S += red[8 + q];
    out[b] = M + logf(S);
  }
}

// ---------------------------------------------------------------------------
// Workspace layout (bytes):
//   E16 : [0, 524288)                 f16 softmax(tran)    512 KB
//   Z   : [524288, 532480)            per-(s,h) row LSE    8 KB
//   C   : [532480, 534528)            emission constant    2 KB
//   UT  : [534528, 534528+81920000)   transposed table     81.9 MB
// ---------------------------------------------------------------------------
extern "C" void kernel_launch(void* const* d_in, const int* in_sizes, int n_in,
                              void* d_out, int out_size, void* d_ws,
                              size_t ws_size, hipStream_t stream) {
  const int* obs = (const int*)d_in[0];
  const int* lengths = (const int*)d_in[1];
  const float* U = (const float*)d_in[2];       // unnormalized_emis (S,H,V)
  const float* tran = (const float*)d_in[3];    // unnormalized_tran (H,H)
  const float* pri = (const float*)d_in[4];     // log_state_priors (H,)
  float* out = (float*)d_out;

  char* ws = (char*)d_ws;
  __half* E16 = (__half*)ws;
  float* Z = (float*)(ws + 524288);
  float* C = (float*)(ws + 532480);
  float* UT = (float*)(ws + 534528);

  const size_t need_ut_bytes = 534528ull + 81920000ull;
  const int use_ut = (ws_size >= need_ut_bytes) ? 1 : 0;

  k_row_lse<<<Sq * Hq, 256, 0, stream>>>(U, Z);
  k_cvec<<<1, 512, 0, stream>>>(Z, C);
  k_tran_softmax<<<Hq, 512, 0, stream>>>(tran, E16);
  if (use_ut) {
    dim3 grid((Vq + 31) / 32, Hq / 32, Sq);
    k_transpose<<<grid, dim3(32, 8), 0, stream>>>(U, UT);
  }
  k_forward<<<Bq, 512, 0, stream>>>(obs, lengths, U, UT, C, E16, pri, out,
                                    use_ut);
}

// Round 3
// 2488.426 us; speedup vs baseline: 1.6724x; 1.0031x over previous
//
#include <hip/hip_runtime.h>
#include <hip/hip_fp16.h>
#include <cstdint>
#include <cstddef>

// Problem constants (match reference)
#define Bq 64
#define Tq 512
#define Sq 4
#define Hq 512
#define Vq 10000

typedef float floatx2 __attribute__((ext_vector_type(2)));

// ln(1024): E is stored as fp8 of (1024 * softmax(tran)) so entries land in
// e4m3's normal range [0.037, 40] (unscaled they'd sit at the subnormal
// granularity 2^-9 and quantize catastrophically).
#define LOG_E_SCALE 6.931471805599453f

// ---------------------------------------------------------------------------
// K1: Z[r] = logsumexp_v U[r, :]  for r in [0, S*H)   (rows of length V)
// ---------------------------------------------------------------------------
__global__ __launch_bounds__(256) void k_row_lse(const float* __restrict__ U,
                                                 float* __restrict__ Z) {
  const int r = blockIdx.x;
  const int tid = threadIdx.x;
  const int lane = tid & 63, wid = tid >> 6;
  __shared__ float sred[8];
  const float4* row = (const float4*)(U + (size_t)r * Vq);  // V=10000 -> 2500 float4
  float m = -1e30f;
  for (int i = tid; i < Vq / 4; i += 256) {
    float4 x = row[i];
    m = fmaxf(fmaxf(m, fmaxf(x.x, x.y)), fmaxf(x.z, x.w));
  }
#pragma unroll
  for (int o = 32; o; o >>= 1) m = fmaxf(m, __shfl_xor(m, o));
  if (lane == 0) sred[wid] = m;
  __syncthreads();
  const float M = fmaxf(fmaxf(sred[0], sred[1]), fmaxf(sred[2], sred[3]));
  float s = 0.f;
  for (int i = tid; i < Vq / 4; i += 256) {
    float4 x = row[i];
    s += expf(x.x - M) + expf(x.y - M) + expf(x.z - M) + expf(x.w - M);
  }
#pragma unroll
  for (int o = 32; o; o >>= 1) s += __shfl_xor(s, o);
  if (lane == 0) sred[4 + wid] = s;
  __syncthreads();
  if (tid == 0) {
    Z[r] = M + logf(sred[4] + sred[5] + sred[6] + sred[7]);
  }
}

// ---------------------------------------------------------------------------
// K2: C[h] = 0.25 * sum_s Z[s*H + h]
// ---------------------------------------------------------------------------
__global__ __launch_bounds__(512) void k_cvec(const float* __restrict__ Z,
                                              float* __restrict__ C) {
  const int h = threadIdx.x;
  C[h] = 0.25f * (Z[h] + Z[Hq + h] + Z[2 * Hq + h] + Z[3 * Hq + h]);
}

// ---------------------------------------------------------------------------
// K3: E8[j,k] = fp8_e4m3( 1024 * softmax_k(tran[j,:]) )   (packed 4/word)
// ---------------------------------------------------------------------------
__global__ __launch_bounds__(512) void k_tran_softmax(const float* __restrict__ tr,
                                                      unsigned int* __restrict__ E8w) {
  const int j = blockIdx.x, tid = threadIdx.x;
  const int lane = tid & 63, wid = tid >> 6;
  __shared__ float sred[16];
  __shared__ float p[Hq];
  const float t = tr[j * Hq + tid];
  float m = t;
#pragma unroll
  for (int o = 32; o; o >>= 1) m = fmaxf(m, __shfl_xor(m, o));
  if (lane == 0) sred[wid] = m;
  __syncthreads();
  float M = sred[0];
#pragma unroll
  for (int q = 1; q < 8; ++q) M = fmaxf(M, sred[q]);
  const float e = expf(t - M);
  float s = e;
#pragma unroll
  for (int o = 32; o; o >>= 1) s += __shfl_xor(s, o);
  if (lane == 0) sred[8 + wid] = s;
  __syncthreads();
  float S = 0.f;
#pragma unroll
  for (int q = 0; q < 8; ++q) S += sred[8 + q];
  p[tid] = 1024.0f * e / S;
  __syncthreads();
  if (tid < 128) {
    int w0 = __builtin_amdgcn_cvt_pk_fp8_f32(p[4 * tid], p[4 * tid + 1], 0, false);
    w0 = __builtin_amdgcn_cvt_pk_fp8_f32(p[4 * tid + 2], p[4 * tid + 3], w0, true);
    E8w[j * 128 + tid] = (unsigned int)w0;
  }
}

// ---------------------------------------------------------------------------
// K4: transpose U (S,H,V) -> UT (S,V,H) so per-(s,v) h-vectors are contiguous
// ---------------------------------------------------------------------------
__global__ __launch_bounds__(256) void k_transpose(const float* __restrict__ U,
                                                   float* __restrict__ UT) {
  __shared__ float tile[32][33];
  const int s = blockIdx.z;
  const int v0 = blockIdx.x * 32, h0 = blockIdx.y * 32;
  const int tx = threadIdx.x, ty = threadIdx.y;  // 32 x 8
#pragma unroll
  for (int q = 0; q < 4; ++q) {
    const int h = h0 + ty + q * 8;
    const int v = v0 + tx;
    if (v < Vq) tile[ty + q * 8][tx] = U[((size_t)s * Hq + h) * Vq + v];
  }
  __syncthreads();
#pragma unroll
  for (int q = 0; q < 4; ++q) {
    const int v = v0 + ty + q * 8;
    if (v < Vq) UT[((size_t)s * Vq + v) * Hq + h0 + tx] = tile[tx][ty + q * 8];
  }
}

// ---------------------------------------------------------------------------
// Emission for one (b,t), state k:  0.25*sum_s table[s][obs_s][k] - C[k]
// ---------------------------------------------------------------------------
__device__ __forceinline__ float emis_at(const float* __restrict__ U,
                                         const float* __restrict__ UT,
                                         const float* __restrict__ C,
                                         const int* __restrict__ ob, int k,
                                         int use_ut) {
  float e;
  if (use_ut) {
    e = UT[((size_t)0 * Vq + ob[0]) * Hq + k] +
        UT[((size_t)1 * Vq + ob[1]) * Hq + k] +
        UT[((size_t)2 * Vq + ob[2]) * Hq + k] +
        UT[((size_t)3 * Vq + ob[3]) * Hq + k];
  } else {
    e = U[((size_t)0 * Hq + k) * Vq + ob[0]] +
        U[((size_t)1 * Hq + k) * Vq + ob[1]] +
        U[((size_t)2 * Hq + k) * Vq + ob[2]] +
        U[((size_t)3 * Hq + k) * Vq + ob[3]];
  }
  return 0.25f * e - C[k];
}

// ---------------------------------------------------------------------------
// K5: forward recursion. One workgroup per batch element b; 512 threads.
// Round-1/2 counters: bound by per-CU L2->L1 bandwidth on streaming E each
// step (f32: 7.85us/step = 1MB/46B/cyc; f16: 4.59us/step). E now fp8
// (256 KB/step). Per step (3 barriers):
//   B1: publish per-wave max of alpha
//   B2: publish w_j = exp(alpha_j - M)
//   matvec: j-group g=tid>>6 covers 64 j's; k-octet i=tid&63 covers k=8i..8i+7
//   B3: publish partials; alpha_k = em + M + log(sum_g part[g][k]) - ln(1024)
// Early-exits at t = lengths[b]-1, then out[b] = logsumexp_k alpha.
// ---------------------------------------------------------------------------
__global__ __launch_bounds__(512) void k_forward(const int* __restrict__ obs,
                                                 const int* __restrict__ lengths,
                                                 const float* __restrict__ U,
                                                 const float* __restrict__ UT,
                                                 const float* __restrict__ C,
                                                 const unsigned int* __restrict__ E8,
                                                 const float* __restrict__ pri,
                                                 float* __restrict__ out,
                                                 int use_ut) {
  const int b = blockIdx.x;
  const int tid = threadIdx.x;           // = state k it owns for alpha
  const int lane = tid & 63, wid = tid >> 6;
  const int L = lengths[b];

  __shared__ float w[Hq];                // 2 KB
  __shared__ float part[8][Hq];          // 16 KB
  __shared__ float red[16];

  // t = 0
  const int* ob0 = obs + ((size_t)b * Tq + 0) * Sq;
  float a = emis_at(U, UT, C, ob0, tid, use_ut) + pri[tid];

  const int g = tid >> 6;   // j-group 0..7 (each covers 64 j)
  const int i = tid & 63;   // k-octet index: k = 8*i .. 8*i+7
  const uint2* E8v = (const uint2*)E8;   // row j: E8v[j*64 + i] = 8 fp8

  for (int t = 1; t < L; ++t) {
    // issue emission gathers early (independent of the reduce/matvec)
    const int* obt = obs + ((size_t)b * Tq + t) * Sq;
    const float emt = emis_at(U, UT, C, obt, tid, use_ut);

    // block max of alpha
    float m = a;
#pragma unroll
    for (int o = 32; o; o >>= 1) m = fmaxf(m, __shfl_xor(m, o));
    if (lane == 0) red[wid] = m;
    __syncthreads();  // B1: red published; prev-iter part reads complete
    float M = red[0];
#pragma unroll
    for (int q = 1; q < 8; ++q) M = fmaxf(M, red[q]);

    w[tid] = expf(a - M);
    __syncthreads();  // B2: w published

    // matvec: k = 8i..8i+7 over j in [g*64, g*64+64)
    float acc0 = 0.f, acc1 = 0.f, acc2 = 0.f, acc3 = 0.f;
    float acc4 = 0.f, acc5 = 0.f, acc6 = 0.f, acc7 = 0.f;
    const int j0 = g << 6;
#pragma unroll 4
    for (int jj = 0; jj < 64; ++jj) {
      const int j = j0 + jj;
      const float wj = w[j];
      const uint2 e = E8v[(size_t)j * 64 + i];
      const floatx2 p0 = __builtin_amdgcn_cvt_pk_f32_fp8(e.x, false);
      const floatx2 p1 = __builtin_amdgcn_cvt_pk_f32_fp8(e.x, true);
      const floatx2 p2 = __builtin_amdgcn_cvt_pk_f32_fp8(e.y, false);
      const floatx2 p3 = __builtin_amdgcn_cvt_pk_f32_fp8(e.y, true);
      acc0 += wj * p0.x;
      acc1 += wj * p0.y;
      acc2 += wj * p1.x;
      acc3 += wj * p1.y;
      acc4 += wj * p2.x;
      acc5 += wj * p2.y;
      acc6 += wj * p3.x;
      acc7 += wj * p3.y;
    }
    {
      float4 lo = {acc0, acc1, acc2, acc3};
      float4 hi = {acc4, acc5, acc6, acc7};
      ((float4*)part[g])[2 * i] = lo;
      ((float4*)part[g])[2 * i + 1] = hi;
    }
    __syncthreads();  // B3: part published; w reads complete

    const float ssum = part[0][tid] + part[1][tid] + part[2][tid] +
                       part[3][tid] + part[4][tid] + part[5][tid] +
                       part[6][tid] + part[7][tid];
    a = emt + M + logf(ssum) - LOG_E_SCALE;
    // part reads above happen-before next B1 -> next part write (post-B2) safe
  }

  // out[b] = logsumexp_k a
  float m = a;
#pragma unroll
  for (int o = 32; o; o >>= 1) m = fmaxf(m, __shfl_xor(m, o));
  if (lane == 0) red[wid] = m;
  __syncthreads();
  float M = red[0];
#pragma unroll
  for (int q = 1; q < 8; ++q) M = fmaxf(M, red[q]);
  float e = expf(a - M);
#pragma unroll
  for (int o = 32; o; o >>= 1) e += __shfl_xor(e, o);
  if (lane == 0) red[8 + wid] = e;
  __syncthreads();
  if (tid == 0) {
    float S = 0.f;
#pragma unroll
    for (int q = 0; q < 8; ++q) S += red[8 + q];
    out[b] = M + logf(S);
  }
}

// ---------------------------------------------------------------------------
// Workspace layout (bytes):
//   E8  : [0, 262144)                 fp8 1024*softmax(tran)  256 KB
//   Z   : [262144, 270336)            per-(s,h) row LSE       8 KB
//   C   : [270336, 272384)            emission constant       2 KB
//   UT  : [272384, 272384+81920000)   transposed table        81.9 MB
// ---------------------------------------------------------------------------
extern "C" void kernel_launch(void* const* d_in, const int* in_sizes, int n_in,
                              void* d_out, int out_size, void* d_ws,
                              size_t ws_size, hipStream_t stream) {
  const int* obs = (const int*)d_in[0];
  const int* lengths = (const int*)d_in[1];
  const float* U = (const float*)d_in[2];       // unnormalized_emis (S,H,V)
  const float* tran = (const float*)d_in[3];    // unnormalized_tran (H,H)
  const float* pri = (const float*)d_in[4];     // log_state_priors (H,)
  float* out = (float*)d_out;

  char* ws = (char*)d_ws;
  unsigned int* E8 = (unsigned int*)ws;
  float* Z = (float*)(ws + 262144);
  float* C = (float*)(ws + 270336);
  float* UT = (float*)(ws + 272384);

  const size_t need_ut_bytes = 272384ull + 81920000ull;
  const int use_ut = (ws_size >= need_ut_bytes) ? 1 : 0;

  k_row_lse<<<Sq * Hq, 256, 0, stream>>>(U, Z);
  k_cvec<<<1, 512, 0, stream>>>(Z, C);
  k_tran_softmax<<<Hq, 512, 0, stream>>>(tran, E8);
  if (use_ut) {
    dim3 grid((Vq + 31) / 32, Hq / 32, Sq);
    k_transpose<<<grid, dim3(32, 8), 0, stream>>>(U, UT);
  }
  k_forward<<<Bq, 512, 0, stream>>>(obs, lengths, U, UT, C, E8, pri, out,
                                    use_ut);
}